// Round 23
// baseline (414.478 us; speedup 1.0000x reference)
//
#include <hip/hip_runtime.h>
#include <hip/hip_bf16.h>
#include <math.h>
#include <stdint.h>

// Problem constants (B,T,E,H,D) = (4,2048,1024,16,64)
constexpr int Bc  = 4;
constexpr int Tc  = 2048;
constexpr int Ec  = 1024;
constexpr int Hc  = 16;
constexpr int Dc  = 64;
constexpr int HDc = Hc * Dc;   // 1024
constexpr int Kc  = Tc;        // 2048 (mems=None)
// softmax scale folded with log2(e): scores computed in log2 domain, exp2f
constexpr float SCL2E = 0.18033688011112042f;  // 0.125 * log2(e)

typedef __bf16 bf16;
typedef __attribute__((ext_vector_type(8))) __bf16 bf16x8;
typedef __attribute__((ext_vector_type(4))) __bf16 bf16x4;
typedef __attribute__((ext_vector_type(4))) float f32x4;
typedef __attribute__((ext_vector_type(4))) _Float16 f16x4;

// ---------------------------------------------------------------------------
// async global->LDS, 16B per lane. LDS dest is wave-uniform base + lane*16.
// ---------------------------------------------------------------------------
__device__ __forceinline__ void gload16(const bf16* gp, bf16* lp) {
  __builtin_amdgcn_global_load_lds(
      (const __attribute__((address_space(1))) void*)gp,
      (__attribute__((address_space(3))) void*)lp, 16, 0, 0);
}

// ---------------------------------------------------------------------------
// Fused prep: pe table + bf16 rounds (we, Wqkv, Wpos, Wout) in ONE launch.
// ---------------------------------------------------------------------------
constexpr int UN_WE   = 2097152;              // we: 8,388,608 f32 / 4
constexpr int UN_QKV  = 786432;               // Wqkv: 3,145,728 / 4
constexpr int UN_WPOS = 262144;               // Wpos: 1,048,576 / 4
constexpr int UN_WOUT = 262144;               // Wout: 1,048,576 / 4 (round)
constexpr int UN_RND  = UN_WE + UN_QKV + UN_WPOS + UN_WOUT;
constexpr int UN_PE   = 262144;               // pe: 1,048,576 pairs / 4
constexpr int UN_TOT  = UN_RND + UN_PE;       // 3,670,016

__global__ __launch_bounds__(256) void prep_kernel(
    const float* __restrict__ we,   bf16* __restrict__ weH,
    const float* __restrict__ Wqkv, bf16* __restrict__ qkvH,
    const float* __restrict__ Wpos, bf16* __restrict__ WposH,
    const float* __restrict__ Wout, bf16* __restrict__ WoutH,
    bf16* __restrict__ peH) {
  int u = blockIdx.x * 256 + threadIdx.x;
  if (u >= UN_TOT) return;
  if (u < UN_RND) {
    const float* src; bf16* dst; int i;
    if (u < UN_WE)                          { src = we;   dst = weH;   i = u * 4; }
    else if (u < UN_WE + UN_QKV)            { src = Wqkv; dst = qkvH;  i = (u - UN_WE) * 4; }
    else if (u < UN_WE + UN_QKV + UN_WPOS)  { src = Wpos; dst = WposH; i = (u - UN_WE - UN_QKV) * 4; }
    else                                    { src = Wout; dst = WoutH; i = (u - UN_WE - UN_QKV - UN_WPOS) * 4; }
    float4 v = *(const float4*)(src + i);
    bf16x4 H = {(bf16)v.x, (bf16)v.y, (bf16)v.z, (bf16)v.w};
    *(bf16x4*)(dst + i) = H;
  } else {
    int p4 = u - UN_RND;             // 4 sin/cos pairs
    int pair0 = p4 * 4;
    int r = pair0 >> 9;              // 512 pairs per row
    int i = pair0 & 511;
    bf16x8 out;
#pragma unroll
    for (int k = 0; k < 4; k++) {
      float div = __expf((float)(i + k) * -0.017988946039015984f);
      float ang = (float)r * div;
      out[2 * k]     = (bf16)sinf(ang);
      out[2 * k + 1] = (bf16)cosf(ang);
    }
    *(bf16x8*)(peH + (size_t)r * Ec + 2 * i) = out;
  }
}

// ---------------------------------------------------------------------------
// MERGED QKV + Rk GEMM (one launch, 1664 blocks; both have K=1024).
// XCD-aware bijective swizzle (1664 = 8*208): each XCD gets a contiguous
// decode range -> A-panel rows reused within one XCD's L2.
// Blocks [0,1536): QKV  C = weH . qkvH^T, EPI-0 scatter (+biases, vT).
// Blocks [1536,1664): Rk C = peH . WposH^T, EPI-1 scatter.
// Dead-tile skip for k/v sections (rows >= ceil64(lens[b]) never read).
// ---------------------------------------------------------------------------
__global__ __launch_bounds__(256) void gemm_qkvrk(
    const bf16* __restrict__ weH, const bf16* __restrict__ qkvH,
    const bf16* __restrict__ peH, const bf16* __restrict__ WposH,
    bf16* __restrict__ qw, bf16* __restrict__ qr,
    bf16* __restrict__ kkp, bf16* __restrict__ vTp,
    bf16* __restrict__ Rkp,
    const float* __restrict__ rwb, const float* __restrict__ rrb,
    const int* __restrict__ lens_) {
  const int bid0 = blockIdx.x;
  const int bid  = (bid0 & 7) * 208 + (bid0 >> 3);   // bijective XCD swizzle
  const bool isQKV = bid < 1536;
  int bn, bm;
  const bf16 *Abase, *Bbase;
  if (isQKV) {
    bn = (bid % 24) * 128;
    bm = (bid / 24) * 128;
    if ((bn >> 10) != 0) {
      int bb = bm >> 11, t0 = bm & 2047;
      int lc = (lens_[bb] + 63) & ~63;
      if (t0 >= lc) return;   // K/V rows never read by attention
    }
    Abase = weH  + (size_t)bm * Ec;
    Bbase = qkvH + (size_t)bn * Ec;
  } else {
    int rr_ = bid - 1536;
    bn = (rr_ % 8) * 128;
    bm = (rr_ / 8) * 128;
    Abase = peH   + (size_t)bm * Ec;
    Bbase = WposH + (size_t)bn * Ec;
  }
  const int tid = threadIdx.x, wv = tid >> 6, lane = tid & 63;
  const int wm = wv >> 1, wn = wv & 1;
  const int g = lane >> 4, laneL = lane & 15;

  __shared__ bf16 lds[2 * 128 * 64];
  bf16* Ah = lds;
  bf16* Bh = lds + 8192;

  f32x4 acc[4][4];
#pragma unroll
  for (int fi = 0; fi < 4; fi++)
#pragma unroll
    for (int fj = 0; fj < 4; fj++) acc[fi][fj] = (f32x4){0.f, 0.f, 0.f, 0.f};

  const int rb  = lane >> 3;
  const int cb8 = ((lane & 7) ^ rb) * 8;

  for (int k0 = 0; k0 < Ec; k0 += 64) {
    __syncthreads();
#pragma unroll
    for (int t = 0; t < 4; t++) {
      int r = t * 32 + wv * 8 + rb;
      size_t go = (size_t)r * Ec + k0 + cb8;
      int lo_ = (t * 32 + wv * 8) * 64;
      gload16(Abase + go, Ah + lo_);
      gload16(Bbase + go, Bh + lo_);
    }
    __syncthreads();
#pragma unroll
    for (int kk = 0; kk < 2; kk++) {
      bf16x8 afh[4], bfh[4];
#pragma unroll
      for (int fi = 0; fi < 4; fi++) {
        int row = wm * 64 + fi * 16 + laneL;
        int off = row * 64 + (((kk * 4 + g) ^ (row & 7)) * 8);
        afh[fi] = *(const bf16x8*)(Ah + off);
      }
#pragma unroll
      for (int fj = 0; fj < 4; fj++) {
        int row = wn * 64 + fj * 16 + laneL;
        int off = row * 64 + (((kk * 4 + g) ^ (row & 7)) * 8);
        bfh[fj] = *(const bf16x8*)(Bh + off);
      }
#pragma unroll
      for (int fi = 0; fi < 4; fi++)
#pragma unroll
        for (int fj = 0; fj < 4; fj++)
          acc[fi][fj] = __builtin_amdgcn_mfma_f32_16x16x32_bf16(afh[fi], bfh[fj], acc[fi][fj], 0, 0, 0);
    }
  }

  if (isQKV) {
#pragma unroll
    for (int fi = 0; fi < 4; fi++) {
#pragma unroll
      for (int fj = 0; fj < 4; fj++) {
        int n = bn + wn * 64 + fj * 16 + laneL;
        int sec = n >> 10, f = n & 1023, hh = f >> 6, d = f & 63;
        float rw = 0.f, rr2 = 0.f;
        if (sec == 0) { rw = rwb[f]; rr2 = rrb[f]; }
#pragma unroll
        for (int rg = 0; rg < 4; rg++) {
          int m = bm + wm * 64 + fi * 16 + g * 4 + rg;
          float cv = acc[fi][fj][rg];
          int bb = m >> 11, t = m & 2047;
          if (sec == 0) {
            size_t o = (((size_t)(bb * Hc + hh)) * Tc + t) * 64 + d;
            qw[o] = (bf16)((cv + rw)  * SCL2E);  // prescaled q+rwb
            qr[o] = (bf16)((cv + rr2) * SCL2E);  // prescaled q+rrb
          } else if (sec == 1) {
            kkp[(((size_t)(bb * Hc + hh)) * Tc + t) * 64 + d] = (bf16)cv;
          } else {
            vTp[(((size_t)(bb * Hc + hh)) * 64 + d) * Tc + t] = (bf16)cv; // vT
          }
        }
      }
    }
  } else {
#pragma unroll
    for (int fi = 0; fi < 4; fi++) {
#pragma unroll
      for (int fj = 0; fj < 4; fj++) {
        int n = bn + wn * 64 + fj * 16 + laneL;
#pragma unroll
        for (int rg = 0; rg < 4; rg++) {
          int m = bm + wm * 64 + fi * 16 + g * 4 + rg;
          Rkp[((size_t)(n >> 6) * Kc + m) * 64 + (n & 63)] = (bf16)acc[fi][fj][rg];
        }
      }
    }
  }
}

// ---------------------------------------------------------------------------
// Out-projection GEMM: out[m,n] = sum_k vec[m,k]*WoutH[n,k], fp32 store.
// 1-D grid (512 = 8*64) with bijective XCD swizzle for A-panel L2 reuse.
// ---------------------------------------------------------------------------
__global__ __launch_bounds__(256) void gemm_out(
    const bf16* __restrict__ Ah_g, const bf16* __restrict__ Bh_g,
    float* __restrict__ o0, int Kd) {
  const int bid0 = blockIdx.x;
  const int bid  = (bid0 & 7) * 64 + (bid0 >> 3);    // bijective XCD swizzle
  const int bn = (bid & 7) * 128;
  const int bm = (bid >> 3) * 128;
  const int tid = threadIdx.x, wv = tid >> 6, lane = tid & 63;
  const int wm = wv >> 1, wn = wv & 1;
  const int g = lane >> 4, laneL = lane & 15;

  __shared__ bf16 lds[2 * 128 * 64];
  bf16* Ah = lds;
  bf16* Bh = lds + 8192;

  f32x4 acc[4][4];
#pragma unroll
  for (int fi = 0; fi < 4; fi++)
#pragma unroll
    for (int fj = 0; fj < 4; fj++) acc[fi][fj] = (f32x4){0.f, 0.f, 0.f, 0.f};

  const int rb  = lane >> 3;
  const int cb8 = ((lane & 7) ^ rb) * 8;
  const bf16* Abase = Ah_g + (size_t)bm * Kd;
  const bf16* Bbase = Bh_g + (size_t)bn * Kd;

  for (int k0 = 0; k0 < Kd; k0 += 64) {
    __syncthreads();
#pragma unroll
    for (int t = 0; t < 4; t++) {
      int r = t * 32 + wv * 8 + rb;
      size_t go = (size_t)r * Kd + k0 + cb8;
      int lo_ = (t * 32 + wv * 8) * 64;
      gload16(Abase + go, Ah + lo_);
      gload16(Bbase + go, Bh + lo_);
    }
    __syncthreads();
#pragma unroll
    for (int kk = 0; kk < 2; kk++) {
      bf16x8 afh[4], bfh[4];
#pragma unroll
      for (int fi = 0; fi < 4; fi++) {
        int row = wm * 64 + fi * 16 + laneL;
        int off = row * 64 + (((kk * 4 + g) ^ (row & 7)) * 8);
        afh[fi] = *(const bf16x8*)(Ah + off);
      }
#pragma unroll
      for (int fj = 0; fj < 4; fj++) {
        int row = wn * 64 + fj * 16 + laneL;
        int off = row * 64 + (((kk * 4 + g) ^ (row & 7)) * 8);
        bfh[fj] = *(const bf16x8*)(Bh + off);
      }
#pragma unroll
      for (int fi = 0; fi < 4; fi++)
#pragma unroll
        for (int fj = 0; fj < 4; fj++)
          acc[fi][fj] = __builtin_amdgcn_mfma_f32_16x16x32_bf16(afh[fi], bfh[fj], acc[fi][fj], 0, 0, 0);
    }
  }

#pragma unroll
  for (int fi = 0; fi < 4; fi++) {
#pragma unroll
    for (int fj = 0; fj < 4; fj++) {
      int n = bn + wn * 64 + fj * 16 + laneL;
#pragma unroll
      for (int rg = 0; rg < 4; rg++) {
        int m = bm + wm * 64 + fi * 16 + g * 4 + rg;
        o0[(size_t)m * 1024 + n] = acc[fi][fj][rg];
      }
    }
  }
}

// ---------------------------------------------------------------------------
// Swapped-operand MFMA fused rel-pos attention, LDS-staged K/V pipeline.
// Measured-best structure (289 us): pair-period barriers, 4 K/V buffers
// (pairs {0,1}/{2,3}); one counted-vmcnt barrier per 2 tiles.
// vmcnt (in-order queue): per period issue stage-pair(8, oldest) -> rkA(10)
// -> rkB(10, newest); cbar vmcnt(20) forces the stage-pair complete and
// leaves both rk sets in flight. Odd-tail tile computed after the loop.
// __launch_bounds__(256,2): 128-VGPR cap; measured best.
// Thresholded defer-max softmax; per-lane l_ reduced once at writeout.
// Rel-shift (T==K): j<=i: BD=(q_i+rr).Rk[T-1+j-i]; j==i+1: 0;
//                   j>=i+2: BD=(q_{i+1}+rr).Rk[j-i-2]
// G per-wave LDS (f16, stride 84, P overlaid); consumer col = 15-laneL+jj,
// p1 = (T-16-c-wv*16)+slot, p2 = (-c-17-wv*16)+slot; c = i0-j0 (mult of 64):
// c>0 -> pure G1; c<0 -> G2 + zero diag (only c=-64 has diag); c==0 mixed.
// ---------------------------------------------------------------------------
__global__ __launch_bounds__(256, 2) void attn_mfma(
    const bf16* __restrict__ qw, const bf16* __restrict__ qr,
    const bf16* __restrict__ kbuf, const bf16* __restrict__ vT,
    const bf16* __restrict__ Rk, const int* __restrict__ lens,
    bf16* __restrict__ vec) {
  // bits: [0:2]=xcd(h hi), [3]=h lo, [4:8]=i0 tile, [9:10]=b  (bijective, 2048)
  const int bid = blockIdx.x;
  const int h  = (bid & 7) * 2 + ((bid >> 3) & 1);
  const int i0 = ((bid >> 4) & 31) * 64;
  const int b  = bid >> 9;
  const int tid = threadIdx.x, wv = tid >> 6, lane = tid & 63;
  const int g = lane >> 4, laneL = lane & 15;
  const int len = lens[b];

  __shared__ __attribute__((aligned(16))) _Float16 Gs[4][16 * 84]; // 10752 B (P overlaid)
  __shared__ bf16 Kst[4][64 * 64];  // 32768 B
  __shared__ bf16 Vst[4][64 * 64];  // 32768 B   total 76288 B -> 2 blk/CU

  const size_t bh = (size_t)(b * Hc + h) * Tc * 64;
  const bf16* qwB = qw   + bh;
  const bf16* qrB = qr   + bh;
  const bf16* kB  = kbuf + bh;
  const bf16* vTB = vT   + bh;
  const bf16* RkB = Rk   + (size_t)h * Kc * 64;

  // Q fragments: lane's own q-row is the MFMA-B row
  const int myrow  = i0 + wv * 16 + laneL;
  const int myrow2 = (myrow + 1 < Tc) ? myrow + 1 : Tc - 1;
  bf16x8 bqw[2], bq1[2], bq2[2];
#pragma unroll
  for (int kk = 0; kk < 2; kk++) {
    bqw[kk] = *(const bf16x8*)(qwB + (size_t)myrow  * 64 + kk * 32 + g * 8);
    bq1[kk] = *(const bf16x8*)(qrB + (size_t)myrow  * 64 + kk * 32 + g * 8);
    bq2[kk] = *(const bf16x8*)(qrB + (size_t)myrow2 * 64 + kk * 32 + g * 8);
  }

  float m_ = -1e30f, l_ = 0.f;   // l_ is PER-LANE partial (16 cols)
  f32x4 O[4];
#pragma unroll
  for (int nf = 0; nf < 4; nf++) O[nf] = (f32x4){0.f, 0.f, 0.f, 0.f};

  _Float16* Gp = &Gs[wv][0];
  bf16*     Pp = (bf16*)&Gs[wv][0];   // OVERLAY: P reuses G space
  const int pswz = (laneL & 7) << 3;

  // ---- staging: wave wv stages K rows [wv*16,+16) and vT rows [wv*16,+16)
  auto stage = [&](int buf, int j0n) __attribute__((always_inline)) {
#pragma unroll
    for (int t = 0; t < 2; t++) {
      const int r0  = wv * 16 + t * 8;
      const int row = r0 + (lane >> 3);
      const int c8  = (lane & 7) ^ ((lane >> 3) & 7);
      gload16(kB  + (size_t)(j0n + row) * 64 + c8 * 8, &Kst[buf][r0 * 64]);
      gload16(vTB + (size_t)row * Tc + j0n + c8 * 8,   &Vst[buf][r0 * 64]);
    }
  };

  // ---- Rk window register prefetch (10 frags; G1 window if c>=0 else G2)
  auto issue_rk = [&](bf16x8 (&rf)[10], int j0n) __attribute__((always_inline)) {
    const int cn = i0 - j0n;
    const int pb = (cn >= 0 ? Tc - 16 - cn : -cn - 17) - wv * 16;
#pragma unroll
    for (int mf = 0; mf < 5; mf++) {
      int p = pb + mf * 16 + laneL;
      p = p < 0 ? 0 : (p > Kc - 1 ? Kc - 1 : p);
#pragma unroll
      for (int kk = 0; kk < 2; kk++)
        rf[mf * 2 + kk] = *(const bf16x8*)(RkB + (size_t)p * 64 + kk * 32 + g * 8);
    }
  };

  auto compute_tile = [&](int cur, int j0c, const bf16x8 (&rf)[10])
      __attribute__((always_inline)) {
    const int c = i0 - j0c;
    const int swz8 = laneL & 7;

    // ---- AC^T from staged K: lane holds S[j=nf*16+4g+r][i=laneL]
    f32x4 ST[4];
    __builtin_amdgcn_s_setprio(1);
#pragma unroll
    for (int nf = 0; nf < 4; nf++) {
      f32x4 acc = (f32x4){0.f, 0.f, 0.f, 0.f};
#pragma unroll
      for (int kk = 0; kk < 2; kk++) {
        bf16x8 bk = *(const bf16x8*)(&Kst[cur][(nf * 16 + laneL) * 64 + (((kk * 4 + g) ^ swz8) * 8)]);
        acc = __builtin_amdgcn_mfma_f32_16x16x32_bf16(bk, bqw[kk], acc, 0, 0, 0);
      }
      ST[nf] = acc;
    }
    __builtin_amdgcn_s_setprio(0);

    const int iic  = wv * 16 + laneL + c;
    const int colb = laneL * 84 + 15 - laneL;
    float P_[4][4];   // BD values -> scores -> exp(P)

    if (c > 0) {
      __builtin_amdgcn_s_setprio(1);
#pragma unroll
      for (int mf = 0; mf < 5; mf++) {
        f32x4 acc = (f32x4){0.f, 0.f, 0.f, 0.f};
#pragma unroll
        for (int kk = 0; kk < 2; kk++)
          acc = __builtin_amdgcn_mfma_f32_16x16x32_bf16(rf[mf * 2 + kk], bq1[kk], acc, 0, 0, 0);
        f16x4 gv = {(_Float16)acc[0], (_Float16)acc[1], (_Float16)acc[2], (_Float16)acc[3]};
        *(f16x4*)(Gp + laneL * 84 + mf * 16 + g * 4) = gv;
      }
      __builtin_amdgcn_s_setprio(0);
#pragma unroll
      for (int nf = 0; nf < 4; nf++)
#pragma unroll
        for (int r = 0; r < 4; r++)
          P_[nf][r] = (float)Gp[colb + nf * 16 + g * 4 + r];
    } else if (c < 0) {
      __builtin_amdgcn_s_setprio(1);
#pragma unroll
      for (int mf = 0; mf < 5; mf++) {
        f32x4 acc = (f32x4){0.f, 0.f, 0.f, 0.f};
#pragma unroll
        for (int kk = 0; kk < 2; kk++)
          acc = __builtin_amdgcn_mfma_f32_16x16x32_bf16(rf[mf * 2 + kk], bq2[kk], acc, 0, 0, 0);
        f16x4 gv = {(_Float16)acc[0], (_Float16)acc[1], (_Float16)acc[2], (_Float16)acc[3]};
        *(f16x4*)(Gp + laneL * 84 + mf * 16 + g * 4) = gv;
      }
      __builtin_amdgcn_s_setprio(0);
#pragma unroll
      for (int nf = 0; nf < 4; nf++)
#pragma unroll
        for (int r = 0; r < 4; r++) {
          const int jj = nf * 16 + g * 4 + r;
          float g2v = (float)Gp[colb + jj];
          P_[nf][r] = (jj == iic + 1) ? 0.f : g2v;
        }
    } else {
      // c == 0: two-pass, pass-1 values parked in P_
      __builtin_amdgcn_s_setprio(1);
#pragma unroll
      for (int mf = 0; mf < 5; mf++) {
        f32x4 acc = (f32x4){0.f, 0.f, 0.f, 0.f};
#pragma unroll
        for (int kk = 0; kk < 2; kk++)
          acc = __builtin_amdgcn_mfma_f32_16x16x32_bf16(rf[mf * 2 + kk], bq1[kk], acc, 0, 0, 0);
        f16x4 gv = {(_Float16)acc[0], (_Float16)acc[1], (_Float16)acc[2], (_Float16)acc[3]};
        *(f16x4*)(Gp + laneL * 84 + mf * 16 + g * 4) = gv;
      }
      __builtin_amdgcn_s_setprio(0);
#pragma unroll
      for (int nf = 0; nf < 4; nf++)
#pragma unroll
        for (int r = 0; r < 4; r++)
          P_[nf][r] = (float)Gp[colb + nf * 16 + g * 4 + r];
      // pass 2: G2 window (inline Rk loads)
      const int pb = -17 - wv * 16;
      __builtin_amdgcn_s_setprio(1);
#pragma unroll
      for (int mf = 0; mf < 5; mf++) {
        int p = pb + mf * 16 + laneL;
        p = p < 0 ? 0 : (p > Kc - 1 ? Kc - 1 : p);
        f32x4 acc = (f32x4){0.f, 0.f, 0.f, 0.f};
#pragma unroll
        for (int kk = 0; kk < 2; kk++) {
          bf16x8 ark = *(const bf16x8*)(RkB + (size_t)p * 64 + kk * 32 + g * 8);
          acc = __builtin_amdgcn_mfma_f32_16x16x32_bf16(ark, bq2[kk], acc, 0, 0, 0);
        }
        f16x4 gv = {(_Float16)acc[0], (_Float16)acc[1], (_Float16)acc[2], (_Float16)acc[3]};
        *(f16x4*)(Gp + laneL * 84 + mf * 16 + g * 4) = gv;
      }
      __builtin_amdgcn_s_setprio(0);
#pragma unroll
      for (int nf = 0; nf < 4; nf++)
#pragma unroll
        for (int r = 0; r < 4; r++) {
          const int jj = nf * 16 + g * 4 + r;
          float g2v = (float)Gp[colb + jj];
          P_[nf][r] = (jj <= iic) ? P_[nf][r] : ((jj == iic + 1) ? 0.f : g2v);
        }
    }

    // ---- scores (log2 domain) + per-lane max
    float pmax = -1e30f;
#pragma unroll
    for (int nf = 0; nf < 4; nf++)
#pragma unroll
      for (int r = 0; r < 4; r++) {
        float s = ST[nf][r] + P_[nf][r];
        P_[nf][r] = s;
        pmax = fmaxf(pmax, s);
      }
    if (j0c + 64 > len) {  // partial last tile only: apply key mask
#pragma unroll
      for (int nf = 0; nf < 4; nf++)
#pragma unroll
        for (int r = 0; r < 4; r++) {
          const int jj = nf * 16 + g * 4 + r;
          if (j0c + jj >= len) P_[nf][r] = -1e30f;
        }
      pmax = -1e30f;
#pragma unroll
      for (int nf = 0; nf < 4; nf++)
#pragma unroll
        for (int r = 0; r < 4; r++) pmax = fmaxf(pmax, P_[nf][r]);
    }

    // ---- thresholded defer-max: shuffles + rescale only on crossing tiles
    if (__any(pmax > m_ + 8.0f)) {
      float rmax = fmaxf(pmax, __shfl_xor(pmax, 16));
      rmax = fmaxf(rmax, __shfl_xor(rmax, 32));
      const float mnew = fmaxf(m_, rmax);
      const float fac = exp2f(m_ - mnew);
      l_ *= fac;
#pragma unroll
      for (int nf = 0; nf < 4; nf++) O[nf] *= fac;
      m_ = mnew;
    }
    float sum = 0.f;
#pragma unroll
    for (int nf = 0; nf < 4; nf++)
#pragma unroll
      for (int r = 0; r < 4; r++) {
        float p = exp2f(P_[nf][r] - m_);
        P_[nf][r] = p;
        sum += p;
      }
    l_ += sum;   // per-lane partial; row-reduced at writeout

    // ---- P -> LDS overlay (G is dead now; compiler barrier for TBAA order)
    asm volatile("" ::: "memory");
#pragma unroll
    for (int mf = 0; mf < 4; mf++) {
      bf16x4 pv = {(bf16)P_[mf][0], (bf16)P_[mf][1], (bf16)P_[mf][2], (bf16)P_[mf][3]};
      *(bf16x4*)(Pp + laneL * 64 + ((mf * 16 + g * 4) ^ pswz)) = pv;
    }

    // ---- PV from staged vT: O^T += mfma(A = vT d-rows, B = P q-rows)
    __builtin_amdgcn_s_setprio(1);
#pragma unroll
    for (int kk = 0; kk < 2; kk++) {
      bf16x8 pbf = *(const bf16x8*)(Pp + laneL * 64 + ((kk * 32 + g * 8) ^ pswz));
#pragma unroll
      for (int nf = 0; nf < 4; nf++) {
        bf16x8 av = *(const bf16x8*)(&Vst[cur][(nf * 16 + laneL) * 64 + (((kk * 4 + g) ^ swz8) * 8)]);
        O[nf] = __builtin_amdgcn_mfma_f32_16x16x32_bf16(av, pbf, O[nf], 0, 0, 0);
      }
    }
    __builtin_amdgcn_s_setprio(0);
  };

  // ---- counted-vmcnt barriers (in-order queue semantics)
  auto cbar20 = [&]() __attribute__((always_inline)) {
    __builtin_amdgcn_sched_barrier(0);
    asm volatile("s_waitcnt vmcnt(20)" ::: "memory");
    __builtin_amdgcn_s_barrier();
    __builtin_amdgcn_sched_barrier(0);
  };
  auto cbar10 = [&]() __attribute__((always_inline)) {
    __builtin_amdgcn_sched_barrier(0);
    asm volatile("s_waitcnt vmcnt(10)" ::: "memory");
    __builtin_amdgcn_s_barrier();
    __builtin_amdgcn_sched_barrier(0);
  };

  // ---- pair-period pipelined j-loop (4-buffer K/V; one barrier per 2 tiles)
  const int ntiles = (len + 63) >> 6;   // >= 2 (len >= 128)
  bf16x8 rfA[10], rfB[10];
  stage(0, 0);
  stage(1, 64);
  issue_rk(rfA, 0);
  issue_rk(rfB, 64);
  __syncthreads();
  int t = 0;
  for (; t + 1 < ntiles; t += 2) {
    const int pp = (t >> 1) & 1;
    const int bA = pp * 2, bB = pp * 2 + 1;
    const int o2 = (pp ^ 1) * 2, o3 = o2 + 1;
    const int j0 = t << 6;
    const bool s2 = (t + 2 < ntiles), s3 = (t + 3 < ntiles);
    if (s2) stage(o2, j0 + 128);
    if (s3) stage(o3, j0 + 192);
    __builtin_amdgcn_sched_barrier(0);
    compute_tile(bA, j0, rfA);
    if (s2) issue_rk(rfA, j0 + 128);
    compute_tile(bB, j0 + 64, rfB);
    if (s3) issue_rk(rfB, j0 + 192);
    if (s3)      cbar20();
    else if (s2) cbar10();
    // else: final period, no barrier needed
  }
  if (t < ntiles) {  // odd tail tile (staged + rk'd by the last full period)
    const int pp = (t >> 1) & 1;
    compute_tile(pp * 2, t << 6, rfA);
  }

  // ---- writeout: row-sum l_ across the 4 g-lanes, then normalize (bf16)
  float lrow = l_ + __shfl_xor(l_, 16);
  lrow += __shfl_xor(lrow, 32);
  const float inv = 1.0f / lrow;
  const size_t rowb = (size_t)(b * Tc + i0 + wv * 16 + laneL) * HDc + h * 64;
#pragma unroll
  for (int nf = 0; nf < 4; nf++) {
    bf16x4 hv = {(bf16)(O[nf][0] * inv), (bf16)(O[nf][1] * inv),
                 (bf16)(O[nf][2] * inv), (bf16)(O[nf][3] * inv)};
    *(bf16x4*)&vec[rowb + nf * 16 + g * 4] = hv;
  }
}

// ---------------------------------------------------------------------------
extern "C" void kernel_launch(void* const* d_in, const int* in_sizes, int n_in,
                              void* d_out, int out_size, void* d_ws, size_t ws_size,
                              hipStream_t stream) {
  const float* we   = (const float*)d_in[0]; // [B,T,E]
  const int*   lens = (const int*)  d_in[1]; // [B]
  const float* Wqkv = (const float*)d_in[2]; // [3*HD, E]
  const float* Wpos = (const float*)d_in[3]; // [HD, E]
  const float* Wout = (const float*)d_in[4]; // [E, HD]
  const float* rwb  = (const float*)d_in[5]; // [H,D]
  const float* rrb  = (const float*)d_in[6]; // [H,D]
  float* out = (float*)d_out;

  // workspace layout (bf16 elems)
  bf16* ws = (bf16*)d_ws;
  const size_t BHTD = (size_t)Bc * Hc * Tc * Dc;   // 8,388,608
  bf16* qw    = ws;
  bf16* qr    = qw    + BHTD;
  bf16* kkp   = qr    + BHTD;
  bf16* vTp   = kkp   + BHTD;
  bf16* Rk    = vTp   + BHTD;
  bf16* peH   = Rk    + (size_t)Hc * Kc * Dc;
  bf16* weH   = peH   + (size_t)Kc * Ec;
  bf16* qkvH  = weH   + BHTD;
  bf16* WposH = qkvH  + (size_t)3 * HDc * Ec;
  bf16* WoutH = WposH + (size_t)HDc * Ec;
  bf16* vec   = WoutH + (size_t)Ec * HDc;
  // total ~ 121 MB

  // 1) single fused prep launch (pe + rounds)
  prep_kernel<<<(UN_TOT + 255) / 256, 256, 0, stream>>>(
      we, weH, Wqkv, qkvH, Wpos, WposH, Wout, WoutH, peH);

  // 2) merged QKV + Rk GEMM (1536 + 128 blocks, one launch, XCD-swizzled)
  gemm_qkvrk<<<1664, 256, 0, stream>>>(
      weH, qkvH, peH, WposH, qw, qr, kkp, vTp, Rk, rwb, rrb, lens);

  // 3) fused attention
  attn_mfma<<<dim3(Tc / 64 * Hc * Bc), 256, 0, stream>>>(
      qw, qr, kkp, vTp, Rk, lens, vec);

  // 4) out projection (XCD-swizzled)
  gemm_out<<<512, 256, 0, stream>>>(
      vec, WoutH, out, HDc);
}

// Round 24
// 393.650 us; speedup vs baseline: 1.0529x; 1.0529x over previous
//
#include <hip/hip_runtime.h>
#include <hip/hip_bf16.h>
#include <math.h>
#include <stdint.h>

// Problem constants (B,T,E,H,D) = (4,2048,1024,16,64)
constexpr int Bc  = 4;
constexpr int Tc  = 2048;
constexpr int Ec  = 1024;
constexpr int Hc  = 16;
constexpr int Dc  = 64;
constexpr int HDc = Hc * Dc;   // 1024
constexpr int Kc  = Tc;        // 2048 (mems=None)
// softmax scale folded with log2(e): scores computed in log2 domain, exp2f
constexpr float SCL2E = 0.18033688011112042f;  // 0.125 * log2(e)

typedef __bf16 bf16;
typedef __attribute__((ext_vector_type(8))) __bf16 bf16x8;
typedef __attribute__((ext_vector_type(4))) __bf16 bf16x4;
typedef __attribute__((ext_vector_type(4))) float f32x4;
typedef __attribute__((ext_vector_type(4))) _Float16 f16x4;

// ---------------------------------------------------------------------------
// async global->LDS, 16B per lane. LDS dest is wave-uniform base + lane*16.
// ---------------------------------------------------------------------------
__device__ __forceinline__ void gload16(const bf16* gp, bf16* lp) {
  __builtin_amdgcn_global_load_lds(
      (const __attribute__((address_space(1))) void*)gp,
      (__attribute__((address_space(3))) void*)lp, 16, 0, 0);
}

// ---------------------------------------------------------------------------
// Fused prep: pe table + bf16 rounds (we, Wqkv, Wpos, Wout) in ONE launch.
// ---------------------------------------------------------------------------
constexpr int UN_WE   = 2097152;              // we: 8,388,608 f32 / 4
constexpr int UN_QKV  = 786432;               // Wqkv: 3,145,728 / 4
constexpr int UN_WPOS = 262144;               // Wpos: 1,048,576 / 4
constexpr int UN_WOUT = 262144;               // Wout: 1,048,576 / 4 (round)
constexpr int UN_RND  = UN_WE + UN_QKV + UN_WPOS + UN_WOUT;
constexpr int UN_PE   = 262144;               // pe: 1,048,576 pairs / 4
constexpr int UN_TOT  = UN_RND + UN_PE;       // 3,670,016

__global__ __launch_bounds__(256) void prep_kernel(
    const float* __restrict__ we,   bf16* __restrict__ weH,
    const float* __restrict__ Wqkv, bf16* __restrict__ qkvH,
    const float* __restrict__ Wpos, bf16* __restrict__ WposH,
    const float* __restrict__ Wout, bf16* __restrict__ WoutH,
    bf16* __restrict__ peH) {
  int u = blockIdx.x * 256 + threadIdx.x;
  if (u >= UN_TOT) return;
  if (u < UN_RND) {
    const float* src; bf16* dst; int i;
    if (u < UN_WE)                          { src = we;   dst = weH;   i = u * 4; }
    else if (u < UN_WE + UN_QKV)            { src = Wqkv; dst = qkvH;  i = (u - UN_WE) * 4; }
    else if (u < UN_WE + UN_QKV + UN_WPOS)  { src = Wpos; dst = WposH; i = (u - UN_WE - UN_QKV) * 4; }
    else                                    { src = Wout; dst = WoutH; i = (u - UN_WE - UN_QKV - UN_WPOS) * 4; }
    float4 v = *(const float4*)(src + i);
    bf16x4 H = {(bf16)v.x, (bf16)v.y, (bf16)v.z, (bf16)v.w};
    *(bf16x4*)(dst + i) = H;
  } else {
    int p4 = u - UN_RND;             // 4 sin/cos pairs
    int pair0 = p4 * 4;
    int r = pair0 >> 9;              // 512 pairs per row
    int i = pair0 & 511;
    bf16x8 out;
#pragma unroll
    for (int k = 0; k < 4; k++) {
      float div = __expf((float)(i + k) * -0.017988946039015984f);
      float ang = (float)r * div;
      out[2 * k]     = (bf16)sinf(ang);
      out[2 * k + 1] = (bf16)cosf(ang);
    }
    *(bf16x8*)(peH + (size_t)r * Ec + 2 * i) = out;
  }
}

// ---------------------------------------------------------------------------
// MERGED QKV + Rk GEMM (one launch, 1664 blocks; both have K=1024).
// Blocks [0,1536): QKV  C = weH . qkvH^T, EPI-0 scatter (+biases, vT).
// Blocks [1536,1664): Rk C = peH . WposH^T, EPI-1 scatter.
// Dead-tile skip for k/v sections (rows >= ceil64(lens[b]) never read).
// NOTE: no XCD swizzle — round 23 measured it re-introduces per-XCD work
// imbalance through the dead-tile skip (contiguous bm range per XCD ->
// one batch per XCD -> stragglers). Default round-robin spreads batches.
// ---------------------------------------------------------------------------
__global__ __launch_bounds__(256) void gemm_qkvrk(
    const bf16* __restrict__ weH, const bf16* __restrict__ qkvH,
    const bf16* __restrict__ peH, const bf16* __restrict__ WposH,
    bf16* __restrict__ qw, bf16* __restrict__ qr,
    bf16* __restrict__ kkp, bf16* __restrict__ vTp,
    bf16* __restrict__ Rkp,
    const float* __restrict__ rwb, const float* __restrict__ rrb,
    const int* __restrict__ lens_) {
  const int bid = blockIdx.x;
  const bool isQKV = bid < 1536;
  int bn, bm;
  const bf16 *Abase, *Bbase;
  if (isQKV) {
    bn = (bid % 24) * 128;
    bm = (bid / 24) * 128;
    if ((bn >> 10) != 0) {
      int bb = bm >> 11, t0 = bm & 2047;
      int lc = (lens_[bb] + 63) & ~63;
      if (t0 >= lc) return;   // K/V rows never read by attention
    }
    Abase = weH  + (size_t)bm * Ec;
    Bbase = qkvH + (size_t)bn * Ec;
  } else {
    int rr_ = bid - 1536;
    bn = (rr_ % 8) * 128;
    bm = (rr_ / 8) * 128;
    Abase = peH   + (size_t)bm * Ec;
    Bbase = WposH + (size_t)bn * Ec;
  }
  const int tid = threadIdx.x, wv = tid >> 6, lane = tid & 63;
  const int wm = wv >> 1, wn = wv & 1;
  const int g = lane >> 4, laneL = lane & 15;

  __shared__ bf16 lds[2 * 128 * 64];
  bf16* Ah = lds;
  bf16* Bh = lds + 8192;

  f32x4 acc[4][4];
#pragma unroll
  for (int fi = 0; fi < 4; fi++)
#pragma unroll
    for (int fj = 0; fj < 4; fj++) acc[fi][fj] = (f32x4){0.f, 0.f, 0.f, 0.f};

  const int rb  = lane >> 3;
  const int cb8 = ((lane & 7) ^ rb) * 8;

  for (int k0 = 0; k0 < Ec; k0 += 64) {
    __syncthreads();
#pragma unroll
    for (int t = 0; t < 4; t++) {
      int r = t * 32 + wv * 8 + rb;
      size_t go = (size_t)r * Ec + k0 + cb8;
      int lo_ = (t * 32 + wv * 8) * 64;
      gload16(Abase + go, Ah + lo_);
      gload16(Bbase + go, Bh + lo_);
    }
    __syncthreads();
#pragma unroll
    for (int kk = 0; kk < 2; kk++) {
      bf16x8 afh[4], bfh[4];
#pragma unroll
      for (int fi = 0; fi < 4; fi++) {
        int row = wm * 64 + fi * 16 + laneL;
        int off = row * 64 + (((kk * 4 + g) ^ (row & 7)) * 8);
        afh[fi] = *(const bf16x8*)(Ah + off);
      }
#pragma unroll
      for (int fj = 0; fj < 4; fj++) {
        int row = wn * 64 + fj * 16 + laneL;
        int off = row * 64 + (((kk * 4 + g) ^ (row & 7)) * 8);
        bfh[fj] = *(const bf16x8*)(Bh + off);
      }
#pragma unroll
      for (int fi = 0; fi < 4; fi++)
#pragma unroll
        for (int fj = 0; fj < 4; fj++)
          acc[fi][fj] = __builtin_amdgcn_mfma_f32_16x16x32_bf16(afh[fi], bfh[fj], acc[fi][fj], 0, 0, 0);
    }
  }

  if (isQKV) {
#pragma unroll
    for (int fi = 0; fi < 4; fi++) {
#pragma unroll
      for (int fj = 0; fj < 4; fj++) {
        int n = bn + wn * 64 + fj * 16 + laneL;
        int sec = n >> 10, f = n & 1023, hh = f >> 6, d = f & 63;
        float rw = 0.f, rr2 = 0.f;
        if (sec == 0) { rw = rwb[f]; rr2 = rrb[f]; }
#pragma unroll
        for (int rg = 0; rg < 4; rg++) {
          int m = bm + wm * 64 + fi * 16 + g * 4 + rg;
          float cv = acc[fi][fj][rg];
          int bb = m >> 11, t = m & 2047;
          if (sec == 0) {
            size_t o = (((size_t)(bb * Hc + hh)) * Tc + t) * 64 + d;
            qw[o] = (bf16)((cv + rw)  * SCL2E);  // prescaled q+rwb
            qr[o] = (bf16)((cv + rr2) * SCL2E);  // prescaled q+rrb
          } else if (sec == 1) {
            kkp[(((size_t)(bb * Hc + hh)) * Tc + t) * 64 + d] = (bf16)cv;
          } else {
            vTp[(((size_t)(bb * Hc + hh)) * 64 + d) * Tc + t] = (bf16)cv; // vT
          }
        }
      }
    }
  } else {
#pragma unroll
    for (int fi = 0; fi < 4; fi++) {
#pragma unroll
      for (int fj = 0; fj < 4; fj++) {
        int n = bn + wn * 64 + fj * 16 + laneL;
#pragma unroll
        for (int rg = 0; rg < 4; rg++) {
          int m = bm + wm * 64 + fi * 16 + g * 4 + rg;
          Rkp[((size_t)(n >> 6) * Kc + m) * 64 + (n & 63)] = (bf16)acc[fi][fj][rg];
        }
      }
    }
  }
}

// ---------------------------------------------------------------------------
// Out-projection GEMM: out[m,n] = sum_k vec[m,k]*WoutH[n,k], fp32 store.
// ---------------------------------------------------------------------------
__global__ __launch_bounds__(256) void gemm_out(
    const bf16* __restrict__ Ah_g, const bf16* __restrict__ Bh_g,
    float* __restrict__ o0, int Kd) {
  const int bn = blockIdx.x * 128, bm = blockIdx.y * 128;
  const int tid = threadIdx.x, wv = tid >> 6, lane = tid & 63;
  const int wm = wv >> 1, wn = wv & 1;
  const int g = lane >> 4, laneL = lane & 15;

  __shared__ bf16 lds[2 * 128 * 64];
  bf16* Ah = lds;
  bf16* Bh = lds + 8192;

  f32x4 acc[4][4];
#pragma unroll
  for (int fi = 0; fi < 4; fi++)
#pragma unroll
    for (int fj = 0; fj < 4; fj++) acc[fi][fj] = (f32x4){0.f, 0.f, 0.f, 0.f};

  const int rb  = lane >> 3;
  const int cb8 = ((lane & 7) ^ rb) * 8;
  const bf16* Abase = Ah_g + (size_t)bm * Kd;
  const bf16* Bbase = Bh_g + (size_t)bn * Kd;

  for (int k0 = 0; k0 < Kd; k0 += 64) {
    __syncthreads();
#pragma unroll
    for (int t = 0; t < 4; t++) {
      int r = t * 32 + wv * 8 + rb;
      size_t go = (size_t)r * Kd + k0 + cb8;
      int lo_ = (t * 32 + wv * 8) * 64;
      gload16(Abase + go, Ah + lo_);
      gload16(Bbase + go, Bh + lo_);
    }
    __syncthreads();
#pragma unroll
    for (int kk = 0; kk < 2; kk++) {
      bf16x8 afh[4], bfh[4];
#pragma unroll
      for (int fi = 0; fi < 4; fi++) {
        int row = wm * 64 + fi * 16 + laneL;
        int off = row * 64 + (((kk * 4 + g) ^ (row & 7)) * 8);
        afh[fi] = *(const bf16x8*)(Ah + off);
      }
#pragma unroll
      for (int fj = 0; fj < 4; fj++) {
        int row = wn * 64 + fj * 16 + laneL;
        int off = row * 64 + (((kk * 4 + g) ^ (row & 7)) * 8);
        bfh[fj] = *(const bf16x8*)(Bh + off);
      }
#pragma unroll
      for (int fi = 0; fi < 4; fi++)
#pragma unroll
        for (int fj = 0; fj < 4; fj++)
          acc[fi][fj] = __builtin_amdgcn_mfma_f32_16x16x32_bf16(afh[fi], bfh[fj], acc[fi][fj], 0, 0, 0);
    }
  }

#pragma unroll
  for (int fi = 0; fi < 4; fi++) {
#pragma unroll
    for (int fj = 0; fj < 4; fj++) {
      int n = bn + wn * 64 + fj * 16 + laneL;
#pragma unroll
      for (int rg = 0; rg < 4; rg++) {
        int m = bm + wm * 64 + fi * 16 + g * 4 + rg;
        o0[(size_t)m * 1024 + n] = acc[fi][fj][rg];
      }
    }
  }
}

// ---------------------------------------------------------------------------
// Swapped-operand MFMA fused rel-pos attention, LDS-staged K/V pipeline.
// Measured-best structure (289 us): pair-period barriers, 4 K/V buffers
// (pairs {0,1}/{2,3}); one counted-vmcnt barrier per 2 tiles.
// vmcnt (in-order queue): per period issue stage-pair(8, oldest) -> rkA(10)
// -> rkB(10, newest); cbar vmcnt(20) forces the stage-pair complete and
// leaves both rk sets in flight. Odd-tail tile computed after the loop.
// __launch_bounds__(256,2): 128-VGPR cap; measured best.
// Thresholded defer-max softmax; per-lane l_ reduced once at writeout.
// Rel-shift (T==K): j<=i: BD=(q_i+rr).Rk[T-1+j-i]; j==i+1: 0;
//                   j>=i+2: BD=(q_{i+1}+rr).Rk[j-i-2]
// G per-wave LDS (f16, stride 84, P overlaid); consumer col = 15-laneL+jj,
// p1 = (T-16-c-wv*16)+slot, p2 = (-c-17-wv*16)+slot; c = i0-j0 (mult of 64):
// c>0 -> pure G1; c<0 -> G2 + zero diag (only c=-64 has diag); c==0 mixed.
// ---------------------------------------------------------------------------
__global__ __launch_bounds__(256, 2) void attn_mfma(
    const bf16* __restrict__ qw, const bf16* __restrict__ qr,
    const bf16* __restrict__ kbuf, const bf16* __restrict__ vT,
    const bf16* __restrict__ Rk, const int* __restrict__ lens,
    bf16* __restrict__ vec) {
  // bits: [0:2]=xcd(h hi), [3]=h lo, [4:8]=i0 tile, [9:10]=b  (bijective, 2048)
  const int bid = blockIdx.x;
  const int h  = (bid & 7) * 2 + ((bid >> 3) & 1);
  const int i0 = ((bid >> 4) & 31) * 64;
  const int b  = bid >> 9;
  const int tid = threadIdx.x, wv = tid >> 6, lane = tid & 63;
  const int g = lane >> 4, laneL = lane & 15;
  const int len = lens[b];

  __shared__ __attribute__((aligned(16))) _Float16 Gs[4][16 * 84]; // 10752 B (P overlaid)
  __shared__ bf16 Kst[4][64 * 64];  // 32768 B
  __shared__ bf16 Vst[4][64 * 64];  // 32768 B   total 76288 B -> 2 blk/CU

  const size_t bh = (size_t)(b * Hc + h) * Tc * 64;
  const bf16* qwB = qw   + bh;
  const bf16* qrB = qr   + bh;
  const bf16* kB  = kbuf + bh;
  const bf16* vTB = vT   + bh;
  const bf16* RkB = Rk   + (size_t)h * Kc * 64;

  // Q fragments: lane's own q-row is the MFMA-B row
  const int myrow  = i0 + wv * 16 + laneL;
  const int myrow2 = (myrow + 1 < Tc) ? myrow + 1 : Tc - 1;
  bf16x8 bqw[2], bq1[2], bq2[2];
#pragma unroll
  for (int kk = 0; kk < 2; kk++) {
    bqw[kk] = *(const bf16x8*)(qwB + (size_t)myrow  * 64 + kk * 32 + g * 8);
    bq1[kk] = *(const bf16x8*)(qrB + (size_t)myrow  * 64 + kk * 32 + g * 8);
    bq2[kk] = *(const bf16x8*)(qrB + (size_t)myrow2 * 64 + kk * 32 + g * 8);
  }

  float m_ = -1e30f, l_ = 0.f;   // l_ is PER-LANE partial (16 cols)
  f32x4 O[4];
#pragma unroll
  for (int nf = 0; nf < 4; nf++) O[nf] = (f32x4){0.f, 0.f, 0.f, 0.f};

  _Float16* Gp = &Gs[wv][0];
  bf16*     Pp = (bf16*)&Gs[wv][0];   // OVERLAY: P reuses G space
  const int pswz = (laneL & 7) << 3;

  // ---- staging: wave wv stages K rows [wv*16,+16) and vT rows [wv*16,+16)
  auto stage = [&](int buf, int j0n) __attribute__((always_inline)) {
#pragma unroll
    for (int t = 0; t < 2; t++) {
      const int r0  = wv * 16 + t * 8;
      const int row = r0 + (lane >> 3);
      const int c8  = (lane & 7) ^ ((lane >> 3) & 7);
      gload16(kB  + (size_t)(j0n + row) * 64 + c8 * 8, &Kst[buf][r0 * 64]);
      gload16(vTB + (size_t)row * Tc + j0n + c8 * 8,   &Vst[buf][r0 * 64]);
    }
  };

  // ---- Rk window register prefetch (10 frags; G1 window if c>=0 else G2)
  auto issue_rk = [&](bf16x8 (&rf)[10], int j0n) __attribute__((always_inline)) {
    const int cn = i0 - j0n;
    const int pb = (cn >= 0 ? Tc - 16 - cn : -cn - 17) - wv * 16;
#pragma unroll
    for (int mf = 0; mf < 5; mf++) {
      int p = pb + mf * 16 + laneL;
      p = p < 0 ? 0 : (p > Kc - 1 ? Kc - 1 : p);
#pragma unroll
      for (int kk = 0; kk < 2; kk++)
        rf[mf * 2 + kk] = *(const bf16x8*)(RkB + (size_t)p * 64 + kk * 32 + g * 8);
    }
  };

  auto compute_tile = [&](int cur, int j0c, const bf16x8 (&rf)[10])
      __attribute__((always_inline)) {
    const int c = i0 - j0c;
    const int swz8 = laneL & 7;

    // ---- AC^T from staged K: lane holds S[j=nf*16+4g+r][i=laneL]
    f32x4 ST[4];
    __builtin_amdgcn_s_setprio(1);
#pragma unroll
    for (int nf = 0; nf < 4; nf++) {
      f32x4 acc = (f32x4){0.f, 0.f, 0.f, 0.f};
#pragma unroll
      for (int kk = 0; kk < 2; kk++) {
        bf16x8 bk = *(const bf16x8*)(&Kst[cur][(nf * 16 + laneL) * 64 + (((kk * 4 + g) ^ swz8) * 8)]);
        acc = __builtin_amdgcn_mfma_f32_16x16x32_bf16(bk, bqw[kk], acc, 0, 0, 0);
      }
      ST[nf] = acc;
    }
    __builtin_amdgcn_s_setprio(0);

    const int iic  = wv * 16 + laneL + c;
    const int colb = laneL * 84 + 15 - laneL;
    float P_[4][4];   // BD values -> scores -> exp(P)

    if (c > 0) {
      __builtin_amdgcn_s_setprio(1);
#pragma unroll
      for (int mf = 0; mf < 5; mf++) {
        f32x4 acc = (f32x4){0.f, 0.f, 0.f, 0.f};
#pragma unroll
        for (int kk = 0; kk < 2; kk++)
          acc = __builtin_amdgcn_mfma_f32_16x16x32_bf16(rf[mf * 2 + kk], bq1[kk], acc, 0, 0, 0);
        f16x4 gv = {(_Float16)acc[0], (_Float16)acc[1], (_Float16)acc[2], (_Float16)acc[3]};
        *(f16x4*)(Gp + laneL * 84 + mf * 16 + g * 4) = gv;
      }
      __builtin_amdgcn_s_setprio(0);
#pragma unroll
      for (int nf = 0; nf < 4; nf++)
#pragma unroll
        for (int r = 0; r < 4; r++)
          P_[nf][r] = (float)Gp[colb + nf * 16 + g * 4 + r];
    } else if (c < 0) {
      __builtin_amdgcn_s_setprio(1);
#pragma unroll
      for (int mf = 0; mf < 5; mf++) {
        f32x4 acc = (f32x4){0.f, 0.f, 0.f, 0.f};
#pragma unroll
        for (int kk = 0; kk < 2; kk++)
          acc = __builtin_amdgcn_mfma_f32_16x16x32_bf16(rf[mf * 2 + kk], bq2[kk], acc, 0, 0, 0);
        f16x4 gv = {(_Float16)acc[0], (_Float16)acc[1], (_Float16)acc[2], (_Float16)acc[3]};
        *(f16x4*)(Gp + laneL * 84 + mf * 16 + g * 4) = gv;
      }
      __builtin_amdgcn_s_setprio(0);
#pragma unroll
      for (int nf = 0; nf < 4; nf++)
#pragma unroll
        for (int r = 0; r < 4; r++) {
          const int jj = nf * 16 + g * 4 + r;
          float g2v = (float)Gp[colb + jj];
          P_[nf][r] = (jj == iic + 1) ? 0.f : g2v;
        }
    } else {
      // c == 0: two-pass, pass-1 values parked in P_
      __builtin_amdgcn_s_setprio(1);
#pragma unroll
      for (int mf = 0; mf < 5; mf++) {
        f32x4 acc = (f32x4){0.f, 0.f, 0.f, 0.f};
#pragma unroll
        for (int kk = 0; kk < 2; kk++)
          acc = __builtin_amdgcn_mfma_f32_16x16x32_bf16(rf[mf * 2 + kk], bq1[kk], acc, 0, 0, 0);
        f16x4 gv = {(_Float16)acc[0], (_Float16)acc[1], (_Float16)acc[2], (_Float16)acc[3]};
        *(f16x4*)(Gp + laneL * 84 + mf * 16 + g * 4) = gv;
      }
      __builtin_amdgcn_s_setprio(0);
#pragma unroll
      for (int nf = 0; nf < 4; nf++)
#pragma unroll
        for (int r = 0; r < 4; r++)
          P_[nf][r] = (float)Gp[colb + nf * 16 + g * 4 + r];
      // pass 2: G2 window (inline Rk loads)
      const int pb = -17 - wv * 16;
      __builtin_amdgcn_s_setprio(1);
#pragma unroll
      for (int mf = 0; mf < 5; mf++) {
        int p = pb + mf * 16 + laneL;
        p = p < 0 ? 0 : (p > Kc - 1 ? Kc - 1 : p);
        f32x4 acc = (f32x4){0.f, 0.f, 0.f, 0.f};
#pragma unroll
        for (int kk = 0; kk < 2; kk++) {
          bf16x8 ark = *(const bf16x8*)(RkB + (size_t)p * 64 + kk * 32 + g * 8);
          acc = __builtin_amdgcn_mfma_f32_16x16x32_bf16(ark, bq2[kk], acc, 0, 0, 0);
        }
        f16x4 gv = {(_Float16)acc[0], (_Float16)acc[1], (_Float16)acc[2], (_Float16)acc[3]};
        *(f16x4*)(Gp + laneL * 84 + mf * 16 + g * 4) = gv;
      }
      __builtin_amdgcn_s_setprio(0);
#pragma unroll
      for (int nf = 0; nf < 4; nf++)
#pragma unroll
        for (int r = 0; r < 4; r++) {
          const int jj = nf * 16 + g * 4 + r;
          float g2v = (float)Gp[colb + jj];
          P_[nf][r] = (jj <= iic) ? P_[nf][r] : ((jj == iic + 1) ? 0.f : g2v);
        }
    }

    // ---- scores (log2 domain) + per-lane max
    float pmax = -1e30f;
#pragma unroll
    for (int nf = 0; nf < 4; nf++)
#pragma unroll
      for (int r = 0; r < 4; r++) {
        float s = ST[nf][r] + P_[nf][r];
        P_[nf][r] = s;
        pmax = fmaxf(pmax, s);
      }
    if (j0c + 64 > len) {  // partial last tile only: apply key mask
#pragma unroll
      for (int nf = 0; nf < 4; nf++)
#pragma unroll
        for (int r = 0; r < 4; r++) {
          const int jj = nf * 16 + g * 4 + r;
          if (j0c + jj >= len) P_[nf][r] = -1e30f;
        }
      pmax = -1e30f;
#pragma unroll
      for (int nf = 0; nf < 4; nf++)
#pragma unroll
        for (int r = 0; r < 4; r++) pmax = fmaxf(pmax, P_[nf][r]);
    }

    // ---- thresholded defer-max: shuffles + rescale only on crossing tiles
    if (__any(pmax > m_ + 8.0f)) {
      float rmax = fmaxf(pmax, __shfl_xor(pmax, 16));
      rmax = fmaxf(rmax, __shfl_xor(rmax, 32));
      const float mnew = fmaxf(m_, rmax);
      const float fac = exp2f(m_ - mnew);
      l_ *= fac;
#pragma unroll
      for (int nf = 0; nf < 4; nf++) O[nf] *= fac;
      m_ = mnew;
    }
    float sum = 0.f;
#pragma unroll
    for (int nf = 0; nf < 4; nf++)
#pragma unroll
      for (int r = 0; r < 4; r++) {
        float p = exp2f(P_[nf][r] - m_);
        P_[nf][r] = p;
        sum += p;
      }
    l_ += sum;   // per-lane partial; row-reduced at writeout

    // ---- P -> LDS overlay (G is dead now; compiler barrier for TBAA order)
    asm volatile("" ::: "memory");
#pragma unroll
    for (int mf = 0; mf < 4; mf++) {
      bf16x4 pv = {(bf16)P_[mf][0], (bf16)P_[mf][1], (bf16)P_[mf][2], (bf16)P_[mf][3]};
      *(bf16x4*)(Pp + laneL * 64 + ((mf * 16 + g * 4) ^ pswz)) = pv;
    }

    // ---- PV from staged vT: O^T += mfma(A = vT d-rows, B = P q-rows)
    __builtin_amdgcn_s_setprio(1);
#pragma unroll
    for (int kk = 0; kk < 2; kk++) {
      bf16x8 pbf = *(const bf16x8*)(Pp + laneL * 64 + ((kk * 32 + g * 8) ^ pswz));
#pragma unroll
      for (int nf = 0; nf < 4; nf++) {
        bf16x8 av = *(const bf16x8*)(&Vst[cur][(nf * 16 + laneL) * 64 + (((kk * 4 + g) ^ swz8) * 8)]);
        O[nf] = __builtin_amdgcn_mfma_f32_16x16x32_bf16(av, pbf, O[nf], 0, 0, 0);
      }
    }
    __builtin_amdgcn_s_setprio(0);
  };

  // ---- counted-vmcnt barriers (in-order queue semantics)
  auto cbar20 = [&]() __attribute__((always_inline)) {
    __builtin_amdgcn_sched_barrier(0);
    asm volatile("s_waitcnt vmcnt(20)" ::: "memory");
    __builtin_amdgcn_s_barrier();
    __builtin_amdgcn_sched_barrier(0);
  };
  auto cbar10 = [&]() __attribute__((always_inline)) {
    __builtin_amdgcn_sched_barrier(0);
    asm volatile("s_waitcnt vmcnt(10)" ::: "memory");
    __builtin_amdgcn_s_barrier();
    __builtin_amdgcn_sched_barrier(0);
  };

  // ---- pair-period pipelined j-loop (4-buffer K/V; one barrier per 2 tiles)
  const int ntiles = (len + 63) >> 6;   // >= 2 (len >= 128)
  bf16x8 rfA[10], rfB[10];
  stage(0, 0);
  stage(1, 64);
  issue_rk(rfA, 0);
  issue_rk(rfB, 64);
  __syncthreads();
  int t = 0;
  for (; t + 1 < ntiles; t += 2) {
    const int pp = (t >> 1) & 1;
    const int bA = pp * 2, bB = pp * 2 + 1;
    const int o2 = (pp ^ 1) * 2, o3 = o2 + 1;
    const int j0 = t << 6;
    const bool s2 = (t + 2 < ntiles), s3 = (t + 3 < ntiles);
    if (s2) stage(o2, j0 + 128);
    if (s3) stage(o3, j0 + 192);
    __builtin_amdgcn_sched_barrier(0);
    compute_tile(bA, j0, rfA);
    if (s2) issue_rk(rfA, j0 + 128);
    compute_tile(bB, j0 + 64, rfB);
    if (s3) issue_rk(rfB, j0 + 192);
    if (s3)      cbar20();
    else if (s2) cbar10();
    // else: final period, no barrier needed
  }
  if (t < ntiles) {  // odd tail tile (staged + rk'd by the last full period)
    const int pp = (t >> 1) & 1;
    compute_tile(pp * 2, t << 6, rfA);
  }

  // ---- writeout: row-sum l_ across the 4 g-lanes, then normalize (bf16)
  float lrow = l_ + __shfl_xor(l_, 16);
  lrow += __shfl_xor(lrow, 32);
  const float inv = 1.0f / lrow;
  const size_t rowb = (size_t)(b * Tc + i0 + wv * 16 + laneL) * HDc + h * 64;
#pragma unroll
  for (int nf = 0; nf < 4; nf++) {
    bf16x4 hv = {(bf16)(O[nf][0] * inv), (bf16)(O[nf][1] * inv),
                 (bf16)(O[nf][2] * inv), (bf16)(O[nf][3] * inv)};
    *(bf16x4*)&vec[rowb + nf * 16 + g * 4] = hv;
  }
}

// ---------------------------------------------------------------------------
extern "C" void kernel_launch(void* const* d_in, const int* in_sizes, int n_in,
                              void* d_out, int out_size, void* d_ws, size_t ws_size,
                              hipStream_t stream) {
  const float* we   = (const float*)d_in[0]; // [B,T,E]
  const int*   lens = (const int*)  d_in[1]; // [B]
  const float* Wqkv = (const float*)d_in[2]; // [3*HD, E]
  const float* Wpos = (const float*)d_in[3]; // [HD, E]
  const float* Wout = (const float*)d_in[4]; // [E, HD]
  const float* rwb  = (const float*)d_in[5]; // [H,D]
  const float* rrb  = (const float*)d_in[6]; // [H,D]
  float* out = (float*)d_out;

  // workspace layout (bf16 elems)
  bf16* ws = (bf16*)d_ws;
  const size_t BHTD = (size_t)Bc * Hc * Tc * Dc;   // 8,388,608
  bf16* qw    = ws;
  bf16* qr    = qw    + BHTD;
  bf16* kkp   = qr    + BHTD;
  bf16* vTp   = kkp   + BHTD;
  bf16* Rk    = vTp   + BHTD;
  bf16* peH   = Rk    + (size_t)Hc * Kc * Dc;
  bf16* weH   = peH   + (size_t)Kc * Ec;
  bf16* qkvH  = weH   + BHTD;
  bf16* WposH = qkvH  + (size_t)3 * HDc * Ec;
  bf16* WoutH = WposH + (size_t)HDc * Ec;
  bf16* vec   = WoutH + (size_t)Ec * HDc;
  // total ~ 121 MB

  // 1) single fused prep launch (pe + rounds)
  prep_kernel<<<(UN_TOT + 255) / 256, 256, 0, stream>>>(
      we, weH, Wqkv, qkvH, Wpos, WposH, Wout, WoutH, peH);

  // 2) merged QKV + Rk GEMM (1536 + 128 blocks, one launch)
  gemm_qkvrk<<<1664, 256, 0, stream>>>(
      weH, qkvH, peH, WposH, qw, qr, kkp, vTp, Rk, rwb, rrb, lens);

  // 3) fused attention
  attn_mfma<<<dim3(Tc / 64 * Hc * Bc), 256, 0, stream>>>(
      qw, qr, kkp, vTp, Rk, lens, vec);

  // 4) out projection
  gemm_out<<<dim3(Ec / 128, (Bc * Tc) / 128), 256, 0, stream>>>(
      vec, WoutH, out, HDc);
}